// Round 3
// baseline (597.863 us; speedup 1.0000x reference)
//
#include <hip/hip_runtime.h>
#include <stdint.h>

#define T_TOK 2048
#define HD 2048
#define FD 1024
#define NE 16
#define NPAIR 8192
#define BM 128
#define MAXTILES 80
#define LDK 40   // BK=32 + 8 pad (80B row stride: 16B-aligned, 2-way-free bank pattern)

typedef short bf16x8 __attribute__((ext_vector_type(8)));
typedef float f32x4 __attribute__((ext_vector_type(4)));
typedef unsigned short u16;

static __device__ __forceinline__ u16 f2bf(float f) {
  uint32_t u = __float_as_uint(f);
  u += 0x7FFFu + ((u >> 16) & 1u);
  return (u16)(u >> 16);
}

// e2m1 nibble -> fp32, times power-of-two scale (exact)
static __device__ __forceinline__ float fp4_val(uint32_t nib, float scale) {
  uint32_t mag = nib & 7u;
  uint32_t big = ((126u + (mag >> 1)) << 23) | ((mag & 1u) << 22); // valid for mag>=2
  uint32_t small = (0u - (mag & 1u)) & 0x3F000000u;                // mag 0 -> 0, mag 1 -> 0.5
  uint32_t bits = (mag >= 2u) ? big : small;
  bits |= (nib & 8u) << 28;
  return __uint_as_float(bits) * scale;
}

// one packed byte (2 e2m1 nibbles, low first) -> dword of 2 packed bf16
static __device__ __forceinline__ uint32_t dq_byte(uint32_t b, float scale) {
  float lo = fp4_val(b & 15u, scale);
  float hi = fp4_val((b >> 4) & 15u, scale);
  return ((uint32_t)(__float_as_uint(lo) >> 16)) | (__float_as_uint(hi) & 0xFFFF0000u);
}

__global__ void cast_kernel(const float* __restrict__ x, u16* __restrict__ xb) {
  int i = blockIdx.x * 256 + threadIdx.x;
  float4 v = ((const float4*)x)[i];
  ushort4 o;
  o.x = f2bf(v.x); o.y = f2bf(v.y); o.z = f2bf(v.z); o.w = f2bf(v.w);
  ((ushort4*)xb)[i] = o;
}

__global__ void zero_kernel(float4* __restrict__ out) {
  out[blockIdx.x * 256 + threadIdx.x] = float4{0.f, 0.f, 0.f, 0.f};
}

__global__ void route_kernel(const int* __restrict__ ids, const float* __restrict__ tw,
                             int* __restrict__ rows, float* __restrict__ rw,
                             int* __restrict__ te) {
  __shared__ int cnt[NE], base[NE], run[NE];
  int tid = threadIdx.x;
  if (tid < NE) { cnt[tid] = 0; run[tid] = 0; }
  __syncthreads();
  for (int i = tid; i < NPAIR; i += 256) atomicAdd(&cnt[ids[i]], 1);
  __syncthreads();
  if (tid == 0) {
    int cum = 0;
    for (int e = 0; e < NE; ++e) {
      base[e] = cum;
      int nt = (cnt[e] + BM - 1) >> 7;
      for (int j = 0; j < nt; ++j) te[(cum >> 7) + j] = e;
      cum += nt << 7;
    }
    for (int t = cum >> 7; t < MAXTILES; ++t) te[t] = -1;
  }
  __syncthreads();
  for (int i = tid; i < MAXTILES * BM; i += 256) { rows[i] = -1; rw[i] = 0.f; }
  __syncthreads();
  for (int i = tid; i < NPAIR; i += 256) {
    int e = ids[i];
    int p = base[e] + atomicAdd(&run[e], 1);
    rows[p] = i >> 2;
    rw[p] = tw[i];
  }
}

// gate_up GEMM + SwiGLU + routing weight -> act (bf16)
// weights read directly in int32-per-packed-byte upload form
__global__ __launch_bounds__(256) void gemm1_kernel(
    const u16* __restrict__ xb, const int* __restrict__ gup32,
    const float* __restrict__ gus, const int* __restrict__ rows,
    const float* __restrict__ rw, const int* __restrict__ te,
    u16* __restrict__ act) {
  const int tile = blockIdx.y;
  const int e = te[tile];
  if (e < 0) return;
  const int f0 = blockIdx.x * 64;

  __shared__ u16 sA[BM * LDK];
  __shared__ u16 sBg[64 * LDK];
  __shared__ u16 sBu[64 * LDK];
  __shared__ int rows_s[BM];
  __shared__ float rw_s[BM];

  const int tid = threadIdx.x;
  if (tid < BM) {
    rows_s[tid] = rows[tile * BM + tid];
    rw_s[tid] = rw[tile * BM + tid];
  }
  __syncthreads();

  const int sm = tid >> 1;
  const int skh = tid & 1;
  int arow = rows_s[sm];
  arow = arow < 0 ? 0 : arow;
  const u16* aptr = xb + (size_t)arow * HD + skh * 16;
  u16* sAp = &sA[sm * LDK + skh * 16];

  const int bn = (tid & 127) >> 1;
  const int isUp = tid >> 7;
  const int o = isUp * 1024 + f0 + bn;
  const int* bptr = gup32 + (size_t)(e * 2048 + o) * (HD / 2) + skh * 8;
  const float* sptr = gus + (size_t)(e * 2048 + o) * (HD / 32);
  u16* sBp = (isUp ? sBu : sBg) + bn * LDK + skh * 16;

  const int lane = tid & 63;
  const int wid = tid >> 6;
  const int wm = wid >> 1, wn = wid & 1;
  const int q = lane >> 4, c = lane & 15;

  f32x4 Cg[4][2], Cu[4][2];
#pragma unroll
  for (int s = 0; s < 4; ++s)
#pragma unroll
    for (int t2 = 0; t2 < 2; ++t2) {
      Cg[s][t2] = f32x4{0.f, 0.f, 0.f, 0.f};
      Cu[s][t2] = f32x4{0.f, 0.f, 0.f, 0.f};
    }

  for (int kk = 0; kk < HD; kk += 32) {
    uint4 av0 = *(const uint4*)(aptr + kk);
    uint4 av1 = *(const uint4*)(aptr + kk + 8);
    int4 w0 = *(const int4*)(bptr + (kk >> 1));
    int4 w1 = *(const int4*)(bptr + (kk >> 1) + 4);
    float sc = sptr[kk >> 5];
    uint32_t d[8];
    d[0] = dq_byte((uint32_t)w0.x, sc);
    d[1] = dq_byte((uint32_t)w0.y, sc);
    d[2] = dq_byte((uint32_t)w0.z, sc);
    d[3] = dq_byte((uint32_t)w0.w, sc);
    d[4] = dq_byte((uint32_t)w1.x, sc);
    d[5] = dq_byte((uint32_t)w1.y, sc);
    d[6] = dq_byte((uint32_t)w1.z, sc);
    d[7] = dq_byte((uint32_t)w1.w, sc);
    *(uint4*)sAp = av0;
    *(uint4*)(sAp + 8) = av1;
    *(uint4*)sBp = make_uint4(d[0], d[1], d[2], d[3]);
    *(uint4*)(sBp + 8) = make_uint4(d[4], d[5], d[6], d[7]);
    __syncthreads();

    bf16x8 af[4], bgf[2], buf_[2];
#pragma unroll
    for (int s = 0; s < 4; ++s)
      af[s] = *(const bf16x8*)&sA[(wm * 64 + s * 16 + c) * LDK + q * 8];
#pragma unroll
    for (int t2 = 0; t2 < 2; ++t2) {
      bgf[t2] = *(const bf16x8*)&sBg[(wn * 32 + t2 * 16 + c) * LDK + q * 8];
      buf_[t2] = *(const bf16x8*)&sBu[(wn * 32 + t2 * 16 + c) * LDK + q * 8];
    }
#pragma unroll
    for (int s = 0; s < 4; ++s)
#pragma unroll
      for (int t2 = 0; t2 < 2; ++t2) {
        Cg[s][t2] = __builtin_amdgcn_mfma_f32_16x16x32_bf16(af[s], bgf[t2], Cg[s][t2], 0, 0, 0);
        Cu[s][t2] = __builtin_amdgcn_mfma_f32_16x16x32_bf16(af[s], buf_[t2], Cu[s][t2], 0, 0, 0);
      }
    __syncthreads();
  }

#pragma unroll
  for (int s = 0; s < 4; ++s) {
    const int mlb = wm * 64 + s * 16 + q * 4;
#pragma unroll
    for (int t2 = 0; t2 < 2; ++t2) {
      const int fg = f0 + wn * 32 + t2 * 16 + c;
#pragma unroll
      for (int r = 0; r < 4; ++r) {
        const int ml = mlb + r;
        float g = Cg[s][t2][r];
        float u = Cu[s][t2][r];
        float aval = g / (1.f + __expf(-g)) * u * rw_s[ml];
        act[(size_t)(tile * BM + ml) * FD + fg] = f2bf(aval);
      }
    }
  }
}

// down GEMM, atomic accumulate into out
__global__ __launch_bounds__(256) void gemm2_kernel(
    const u16* __restrict__ act, const int* __restrict__ dwn32,
    const float* __restrict__ dsc, const int* __restrict__ rows,
    const int* __restrict__ te, float* __restrict__ out) {
  const int tile = blockIdx.y;
  const int e = te[tile];
  if (e < 0) return;
  const int h0 = blockIdx.x * 64;

  __shared__ u16 sA[BM * LDK];
  __shared__ u16 sB[64 * LDK];
  __shared__ int rows_s[BM];

  const int tid = threadIdx.x;
  if (tid < BM) rows_s[tid] = rows[tile * BM + tid];
  __syncthreads();

  const int sm = tid >> 1;
  const int skh = tid & 1;
  const u16* aptr = act + (size_t)(tile * BM + sm) * FD + skh * 16;
  u16* sAp = &sA[sm * LDK + skh * 16];

  const int bn2 = tid >> 2;
  const int kq = tid & 3;
  const int* bptr = dwn32 + (size_t)(e * 2048 + h0 + bn2) * (FD / 2) + kq * 4;
  const float* sptr = dsc + (size_t)(e * 2048 + h0 + bn2) * (FD / 32);
  u16* sBp = &sB[bn2 * LDK + kq * 8];

  const int lane = tid & 63;
  const int wid = tid >> 6;
  const int wm = wid >> 1, wn = wid & 1;
  const int q = lane >> 4, c = lane & 15;

  f32x4 Cd[4][2];
#pragma unroll
  for (int s = 0; s < 4; ++s)
#pragma unroll
    for (int t2 = 0; t2 < 2; ++t2) Cd[s][t2] = f32x4{0.f, 0.f, 0.f, 0.f};

  for (int kk = 0; kk < FD; kk += 32) {
    uint4 av0 = *(const uint4*)(aptr + kk);
    uint4 av1 = *(const uint4*)(aptr + kk + 8);
    int4 w = *(const int4*)(bptr + (kk >> 1));
    float sc = sptr[kk >> 5];
    uint32_t d[4];
    d[0] = dq_byte((uint32_t)w.x, sc);
    d[1] = dq_byte((uint32_t)w.y, sc);
    d[2] = dq_byte((uint32_t)w.z, sc);
    d[3] = dq_byte((uint32_t)w.w, sc);
    *(uint4*)sAp = av0;
    *(uint4*)(sAp + 8) = av1;
    *(uint4*)sBp = make_uint4(d[0], d[1], d[2], d[3]);
    __syncthreads();

    bf16x8 af[4], bf_[2];
#pragma unroll
    for (int s = 0; s < 4; ++s)
      af[s] = *(const bf16x8*)&sA[(wm * 64 + s * 16 + c) * LDK + q * 8];
#pragma unroll
    for (int t2 = 0; t2 < 2; ++t2)
      bf_[t2] = *(const bf16x8*)&sB[(wn * 32 + t2 * 16 + c) * LDK + q * 8];
#pragma unroll
    for (int s = 0; s < 4; ++s)
#pragma unroll
      for (int t2 = 0; t2 < 2; ++t2)
        Cd[s][t2] = __builtin_amdgcn_mfma_f32_16x16x32_bf16(af[s], bf_[t2], Cd[s][t2], 0, 0, 0);
    __syncthreads();
  }

#pragma unroll
  for (int s = 0; s < 4; ++s) {
    const int mlb = wm * 64 + s * 16 + q * 4;
#pragma unroll
    for (int t2 = 0; t2 < 2; ++t2) {
      const int hg = h0 + wn * 32 + t2 * 16 + c;
#pragma unroll
      for (int r = 0; r < 4; ++r) {
        int token = rows_s[mlb + r];
        if (token >= 0) atomicAdd(&out[(size_t)token * HD + hg], Cd[s][t2][r]);
      }
    }
  }
}

extern "C" void kernel_launch(void* const* d_in, const int* in_sizes, int n_in,
                              void* d_out, int out_size, void* d_ws, size_t ws_size,
                              hipStream_t stream) {
  const float* hidden = (const float*)d_in[0];
  const float* tw = (const float*)d_in[1];
  const int* ids = (const int*)d_in[2];
  const int* gup32 = (const int*)d_in[3];   // uint8 packed bytes, uploaded as int32
  const float* gus = (const float*)d_in[4];
  const int* dwn32 = (const int*)d_in[5];   // uint8 packed bytes, uploaded as int32
  const float* dsc = (const float*)d_in[6];
  float* out = (float*)d_out;

  // ws usage capped at ~28.2 MB (no repack buffers — round-2 79.8 MB layout
  // likely OOB-wrote past ws_size and corrupted harness pristine buffers)
  char* ws = (char*)d_ws;
  int* rows = (int*)(ws);                               // 40 KB
  float* rw = (float*)(ws + 49152);                     // 40 KB
  int* te = (int*)(ws + 98304);                         // 320 B
  u16* xb = (u16*)(ws + 131072);                        // 8 MB
  u16* act = (u16*)(ws + 131072 + 8388608);             // 20 MB -> total 29,491,200 B

  cast_kernel<<<dim3(4096), dim3(256), 0, stream>>>(hidden, xb);
  zero_kernel<<<dim3(4096), dim3(256), 0, stream>>>((float4*)out);
  route_kernel<<<dim3(1), dim3(256), 0, stream>>>(ids, tw, rows, rw, te);
  gemm1_kernel<<<dim3(16, MAXTILES), dim3(256), 0, stream>>>(xb, gup32, gus, rows, rw, te, act);
  gemm2_kernel<<<dim3(32, MAXTILES), dim3(256), 0, stream>>>(act, dwn32, dsc, rows, te, out);
}